// Round 1
// baseline (415.826 us; speedup 1.0000x reference)
//
#include <hip/hip_runtime.h>
#include <hip/hip_bf16.h>
#include <cstdint>
#include <cstddef>

// ---------------------------------------------------------------------------
// Problem: B=4, N=1024, C=256, H=8, hd=32, ALPHA=0.6
// Math simplification:
//   softmax rows sum to 1  =>  S_x = attn_x^T (d-normalization == 1)
//   A_rd @ vd = alpha * attn_r^T @ (attn_d @ vd) + (1-alpha)*(attn_r+attn_d)@vd
// So only N^2-by-small matmuls are needed.
// Pipeline (all fp32 accumulate; attn stored bf16):
//   K1 proj:    qkv[br][b][n][768] = x[...,br-half] @ w_br^T
//   K2 qk+sm:   attn[br][bh][n][m] (bf16)
//   K3 av:      OX[br][bh][n][0:32]=attn_br@vr, [32:64]=attn_br@vd
//   K4 uo:      U[0][bh][d][n] = sum_k O_d[k,d]*attn_r[k,n]   (O_d = OX[1][..][32:])
//               U[1][bh][d][n] = sum_k O_r[k,d]*attn_d[k,n]   (O_r = OX[0][..][:32])
//   K5 combine: out_dr, out_rd, out_r, out_d
// ---------------------------------------------------------------------------

#define ALPHA_F 0.6f
#define OMA_F   0.4f
#define SCALE_F 0.17677669529663687f  // 1/sqrt(32)

static const size_t WS_QKV_OFF  = 0;                       // 2*4096*768 f32 = 25165824 B
static const size_t WS_ATTN_OFF = 25165824ull;             // 2*32*1024*1024 bf16 = 134217728 B
static const size_t WS_OX_OFF   = 25165824ull + 134217728ull;            // 2*32*1024*64 f32 = 16777216 B
static const size_t WS_U_OFF    = 25165824ull + 134217728ull + 16777216ull; // 2*32*32*1024 f32 = 8388608 B

__device__ __forceinline__ float bf2f(unsigned short u) {
  union { unsigned int i; float f; } v; v.i = ((unsigned int)u) << 16; return v.f;
}
__device__ __forceinline__ float bflo(unsigned int u) {
  union { unsigned int i; float f; } v; v.i = u << 16; return v.f;
}
__device__ __forceinline__ float bfhi(unsigned int u) {
  union { unsigned int i; float f; } v; v.i = u & 0xffff0000u; return v.f;
}
__device__ __forceinline__ unsigned short f2bf(float f) {
  union { float f; unsigned int i; } v; v.f = f;
  unsigned int r = v.i + 0x7fffu + ((v.i >> 16) & 1u);
  return (unsigned short)(r >> 16);
}

// ---------------------------------------------------------------------------
// K1: projection GEMM.  M=8192 (br*4096 + b*1024 + n), N=768, K=256.
// C[m][j] = sum_k A[m][k]*B[j][k];  A row = x[b,n, br*256 + k], B = w_br[j][k]
// Tile 64x64, K-step 32.  LDS stored K-major (transposed) for vector reads.
__global__ __launch_bounds__(256) void k_proj(const float* __restrict__ x,
                                              const float* __restrict__ wr,
                                              const float* __restrict__ wd,
                                              float* __restrict__ qkv) {
  __shared__ float As[32][68];  // [k][m-row]
  __shared__ float Bs[32][68];  // [k][j-col]
  const int t  = threadIdx.x;
  const int m0 = blockIdx.x * 64;
  const int j0 = blockIdx.y * 64;
  const int br = m0 >> 12;           // 4096 rows per branch; 64 | 4096
  const float* w = br ? wd : wr;
  const int bn0 = m0 & 4095;
  const int tx = t & 15, ty = t >> 4;
  const int lr = t >> 2;             // 0..63
  const int lk = (t & 3) * 8;        // 0,8,16,24
  const float* xbase = x + (size_t)(bn0 + lr) * 512 + br * 256 + lk;
  const float* wbase = w + (size_t)(j0 + lr) * 256 + lk;
  float acc[4][4] = {};
  for (int k0 = 0; k0 < 256; k0 += 32) {
    float4 a0 = *(const float4*)(xbase + k0);
    float4 a1 = *(const float4*)(xbase + k0 + 4);
    float4 b0 = *(const float4*)(wbase + k0);
    float4 b1 = *(const float4*)(wbase + k0 + 4);
    __syncthreads();
    As[lk + 0][lr] = a0.x; As[lk + 1][lr] = a0.y; As[lk + 2][lr] = a0.z; As[lk + 3][lr] = a0.w;
    As[lk + 4][lr] = a1.x; As[lk + 5][lr] = a1.y; As[lk + 6][lr] = a1.z; As[lk + 7][lr] = a1.w;
    Bs[lk + 0][lr] = b0.x; Bs[lk + 1][lr] = b0.y; Bs[lk + 2][lr] = b0.z; Bs[lk + 3][lr] = b0.w;
    Bs[lk + 4][lr] = b1.x; Bs[lk + 5][lr] = b1.y; Bs[lk + 6][lr] = b1.z; Bs[lk + 7][lr] = b1.w;
    __syncthreads();
#pragma unroll
    for (int kk = 0; kk < 32; ++kk) {
      float4 a = *(const float4*)&As[kk][ty * 4];
      float4 b = *(const float4*)&Bs[kk][tx * 4];
      acc[0][0] += a.x * b.x; acc[0][1] += a.x * b.y; acc[0][2] += a.x * b.z; acc[0][3] += a.x * b.w;
      acc[1][0] += a.y * b.x; acc[1][1] += a.y * b.y; acc[1][2] += a.y * b.z; acc[1][3] += a.y * b.w;
      acc[2][0] += a.z * b.x; acc[2][1] += a.z * b.y; acc[2][2] += a.z * b.z; acc[2][3] += a.z * b.w;
      acc[3][0] += a.w * b.x; acc[3][1] += a.w * b.y; acc[3][2] += a.w * b.z; acc[3][3] += a.w * b.w;
    }
  }
#pragma unroll
  for (int i = 0; i < 4; ++i) {
    float4 v = make_float4(acc[i][0], acc[i][1], acc[i][2], acc[i][3]);
    *(float4*)(qkv + (size_t)(m0 + ty * 4 + i) * 768 + j0 + tx * 4) = v;
  }
}

// ---------------------------------------------------------------------------
// K2: QK^T * scale, row softmax, write bf16 attn.
// Block: one (br,bh), 16 rows. 16 lanes per row, 64 logits/lane in registers.
__global__ __launch_bounds__(256) void k_qk_softmax(const float* __restrict__ qkv,
                                                    unsigned short* __restrict__ attn) {
  __shared__ float qs[16][32];
  __shared__ float ks[128][36];
  __shared__ unsigned short outs[16][128];
  const int t = threadIdx.x;
  const int bb = blockIdx.x;             // br*32 + bh
  const int br = bb >> 5, bh = bb & 31;
  const int b = bh >> 3, h = bh & 7;
  const int row0 = blockIdx.y * 16;
  const size_t qbase = (size_t)(br * 4096 + b * 1024) * 768;
  if (t < 128) {
    int r = t >> 3, d4 = (t & 7) * 4;
    *(float4*)&qs[r][d4] = *(const float4*)(qkv + qbase + (size_t)(row0 + r) * 768 + h * 32 + d4);
  }
  __syncthreads();
  const int row = t >> 4, ci = t & 15;
  float4 qv[8];
#pragma unroll
  for (int i = 0; i < 8; ++i) qv[i] = *(const float4*)&qs[row][i * 4];
  float lg[64];
#pragma unroll
  for (int ct = 0; ct < 8; ++ct) {
    __syncthreads();
    {
      int r = t >> 1, d0 = (t & 1) * 16;
      const float* kb = qkv + qbase + (size_t)(ct * 128 + r) * 768 + 256 + h * 32 + d0;
      *(float4*)&ks[r][d0]      = *(const float4*)(kb);
      *(float4*)&ks[r][d0 + 4]  = *(const float4*)(kb + 4);
      *(float4*)&ks[r][d0 + 8]  = *(const float4*)(kb + 8);
      *(float4*)&ks[r][d0 + 12] = *(const float4*)(kb + 12);
    }
    __syncthreads();
#pragma unroll
    for (int jj = 0; jj < 8; ++jj) {
      int c = ci + jj * 16;
      float acc = 0.f;
#pragma unroll
      for (int d4 = 0; d4 < 8; ++d4) {
        float4 kv = *(const float4*)&ks[c][d4 * 4];
        acc += qv[d4].x * kv.x + qv[d4].y * kv.y + qv[d4].z * kv.z + qv[d4].w * kv.w;
      }
      lg[ct * 8 + jj] = acc * SCALE_F;
    }
  }
  float m = -1e30f;
#pragma unroll
  for (int i = 0; i < 64; ++i) m = fmaxf(m, lg[i]);
#pragma unroll
  for (int x = 1; x < 16; x <<= 1) m = fmaxf(m, __shfl_xor(m, x, 64));
  float s = 0.f;
#pragma unroll
  for (int i = 0; i < 64; ++i) { lg[i] = __expf(lg[i] - m); s += lg[i]; }
#pragma unroll
  for (int x = 1; x < 16; x <<= 1) s += __shfl_xor(s, x, 64);
  const float rinv = 1.0f / s;
  const size_t abase = ((size_t)bb * 1024 + row0) * 1024;
#pragma unroll
  for (int ct = 0; ct < 8; ++ct) {
    __syncthreads();
#pragma unroll
    for (int jj = 0; jj < 8; ++jj) outs[row][ci + jj * 16] = f2bf(lg[ct * 8 + jj] * rinv);
    __syncthreads();
    uint4 vv = *(const uint4*)&outs[t >> 4][(t & 15) * 8];
    *(uint4*)(attn + abase + (size_t)(t >> 4) * 1024 + ct * 128 + (t & 15) * 8) = vv;
  }
}

// ---------------------------------------------------------------------------
// K3: OX[br][bh][n][0:64] = attn_br @ [vr | vd].  Tile 64 rows x 64 cols, K-step 64.
__global__ __launch_bounds__(256) void k_av(const unsigned short* __restrict__ attn,
                                            const float* __restrict__ qkv,
                                            float* __restrict__ OX) {
  __shared__ unsigned short As[64][72];  // [n-row][k] bf16
  __shared__ float Bs[64][68];           // [k][j]
  const int t = threadIdx.x;
  const int bb = blockIdx.x;
  const int bh = bb & 31, b = bh >> 3, h = bh & 7;
  const int n0 = blockIdx.y * 64;
  const int tx = t & 15, ty = t >> 4;
  const size_t abase = (size_t)bb * 1024 * 1024;
  const int lr = t >> 2;
  const int lj = (t & 3) * 16;  // 0,16,32,48
  const float* vb = qkv + (size_t)((lj >= 32 ? 4096 : 0) + b * 1024) * 768 + 512 + h * 32 + (lj & 31);
  const unsigned short* ab = attn + abase + (size_t)(n0 + lr) * 1024 + (t & 3) * 16;
  float acc[4][4] = {};
  for (int k0 = 0; k0 < 1024; k0 += 64) {
    uint4 a01 = *(const uint4*)(ab + k0);
    uint4 a23 = *(const uint4*)(ab + k0 + 8);
    const float* vrow = vb + (size_t)(k0 + lr) * 768;
    float4 v0 = *(const float4*)(vrow);
    float4 v1 = *(const float4*)(vrow + 4);
    float4 v2 = *(const float4*)(vrow + 8);
    float4 v3 = *(const float4*)(vrow + 12);
    __syncthreads();
    *(uint4*)&As[lr][(t & 3) * 16]     = a01;
    *(uint4*)&As[lr][(t & 3) * 16 + 8] = a23;
    *(float4*)&Bs[lr][lj]      = v0;
    *(float4*)&Bs[lr][lj + 4]  = v1;
    *(float4*)&Bs[lr][lj + 8]  = v2;
    *(float4*)&Bs[lr][lj + 12] = v3;
    __syncthreads();
#pragma unroll
    for (int kk = 0; kk < 64; ++kk) {
      float4 bv = *(const float4*)&Bs[kk][tx * 4];
      float a0 = bf2f(As[ty * 4 + 0][kk]);
      float a1 = bf2f(As[ty * 4 + 1][kk]);
      float a2 = bf2f(As[ty * 4 + 2][kk]);
      float a3 = bf2f(As[ty * 4 + 3][kk]);
      acc[0][0] += a0 * bv.x; acc[0][1] += a0 * bv.y; acc[0][2] += a0 * bv.z; acc[0][3] += a0 * bv.w;
      acc[1][0] += a1 * bv.x; acc[1][1] += a1 * bv.y; acc[1][2] += a1 * bv.z; acc[1][3] += a1 * bv.w;
      acc[2][0] += a2 * bv.x; acc[2][1] += a2 * bv.y; acc[2][2] += a2 * bv.z; acc[2][3] += a2 * bv.w;
      acc[3][0] += a3 * bv.x; acc[3][1] += a3 * bv.y; acc[3][2] += a3 * bv.z; acc[3][3] += a3 * bv.w;
    }
  }
#pragma unroll
  for (int i = 0; i < 4; ++i) {
    float4 v = make_float4(acc[i][0], acc[i][1], acc[i][2], acc[i][3]);
    *(float4*)(OX + ((size_t)bb * 1024 + n0 + ty * 4 + i) * 64 + tx * 4) = v;
  }
}

// ---------------------------------------------------------------------------
// K4: U[p][bh][d][n] = sum_k O[k][d] * attn[k][n].  Output tile 32x128, K-step 64.
__global__ __launch_bounds__(256) void k_uo(const unsigned short* __restrict__ attn,
                                            const float* __restrict__ OX,
                                            float* __restrict__ U) {
  __shared__ float Os[64][36];           // [k][d]
  __shared__ unsigned short As[64][136]; // [k][n] bf16
  const int t = threadIdx.x;
  const int pb = blockIdx.x;             // p*32 + bh
  const int p = pb >> 5, bh = pb & 31;
  const int nb = blockIdx.y;             // n0 = nb*128
  const float* ob = OX + ((size_t)((p == 0 ? 1 : 0) * 32 + bh) * 1024) * 64 + (p == 0 ? 32 : 0);
  const unsigned short* ab = attn + (size_t)((p == 0 ? 0 : 1) * 32 + bh) * 1024 * 1024 + nb * 128;
  const int tx = t & 31, ty = t >> 5;
  const int lr = t >> 2;
  const int lc = (t & 3);
  float acc[4][4] = {};
  for (int k0 = 0; k0 < 1024; k0 += 64) {
    const float* orow = ob + (size_t)(k0 + lr) * 64 + lc * 8;
    float4 o0 = *(const float4*)(orow);
    float4 o1 = *(const float4*)(orow + 4);
    const unsigned short* arow = ab + (size_t)(k0 + lr) * 1024 + lc * 32;
    uint4 a0 = *(const uint4*)(arow);
    uint4 a1 = *(const uint4*)(arow + 8);
    uint4 a2 = *(const uint4*)(arow + 16);
    uint4 a3 = *(const uint4*)(arow + 24);
    __syncthreads();
    *(float4*)&Os[lr][lc * 8]     = o0;
    *(float4*)&Os[lr][lc * 8 + 4] = o1;
    *(uint4*)&As[lr][lc * 32]      = a0;
    *(uint4*)&As[lr][lc * 32 + 8]  = a1;
    *(uint4*)&As[lr][lc * 32 + 16] = a2;
    *(uint4*)&As[lr][lc * 32 + 24] = a3;
    __syncthreads();
#pragma unroll
    for (int kk = 0; kk < 64; ++kk) {
      float4 av = *(const float4*)&Os[kk][ty * 4];
      uint2 bv = *(const uint2*)&As[kk][tx * 4];
      float b0 = bflo(bv.x), b1 = bfhi(bv.x), b2 = bflo(bv.y), b3 = bfhi(bv.y);
      acc[0][0] += av.x * b0; acc[0][1] += av.x * b1; acc[0][2] += av.x * b2; acc[0][3] += av.x * b3;
      acc[1][0] += av.y * b0; acc[1][1] += av.y * b1; acc[1][2] += av.y * b2; acc[1][3] += av.y * b3;
      acc[2][0] += av.z * b0; acc[2][1] += av.z * b1; acc[2][2] += av.z * b2; acc[2][3] += av.z * b3;
      acc[3][0] += av.w * b0; acc[3][1] += av.w * b1; acc[3][2] += av.w * b2; acc[3][3] += av.w * b3;
    }
  }
#pragma unroll
  for (int i = 0; i < 4; ++i) {
    float4 v = make_float4(acc[i][0], acc[i][1], acc[i][2], acc[i][3]);
    *(float4*)(U + ((size_t)pb * 32 + ty * 4 + i) * 1024 + nb * 128 + tx * 4) = v;
  }
}

// ---------------------------------------------------------------------------
// K5: combine + head-interleave.  One block per (o,b,n); 256 threads = h*32+d.
__global__ __launch_bounds__(256) void k_combine(const float* __restrict__ OX,
                                                 const float* __restrict__ U,
                                                 float* __restrict__ out) {
  const int idx = blockIdx.x;
  const int n = idx & 1023;
  const int ob = idx >> 10;
  const int b = ob & 3, o = ob >> 2;
  const int t = threadIdx.x;
  const int h = t >> 5, d = t & 31;
  const int bh = b * 8 + h;
  const size_t x0 = ((size_t)bh * 1024 + n) * 64;         // br=0 row
  const size_t x1 = ((size_t)(32 + bh) * 1024 + n) * 64;  // br=1 row
  float r;
  if (o == 0) {        // out_dr = a*U_dr[d,n] + (1-a)*(X_dr + O_r)
    r = ALPHA_F * U[((size_t)(32 + bh) * 32 + d) * 1024 + n] + OMA_F * (OX[x1 + d] + OX[x0 + d]);
  } else if (o == 1) { // out_rd = a*U_rd[d,n] + (1-a)*(X_rd + O_d)
    r = ALPHA_F * U[((size_t)bh * 32 + d) * 1024 + n] + OMA_F * (OX[x0 + 32 + d] + OX[x1 + 32 + d]);
  } else if (o == 2) { // out_r
    r = OX[x0 + d];
  } else {             // out_d
    r = OX[x1 + 32 + d];
  }
  out[((size_t)(o * 4 + b) * 1024 + n) * 256 + t] = r;
}

// ---------------------------------------------------------------------------
extern "C" void kernel_launch(void* const* d_in, const int* in_sizes, int n_in,
                              void* d_out, int out_size, void* d_ws, size_t ws_size,
                              hipStream_t stream) {
  const float* x  = (const float*)d_in[0];
  const float* wr = (const float*)d_in[1];
  const float* wd = (const float*)d_in[2];
  float* out = (float*)d_out;
  char* ws = (char*)d_ws;
  float* qkv = (float*)(ws + WS_QKV_OFF);
  unsigned short* attn = (unsigned short*)(ws + WS_ATTN_OFF);
  float* OX = (float*)(ws + WS_OX_OFF);
  float* U  = (float*)(ws + WS_U_OFF);

  k_proj<<<dim3(128, 12), 256, 0, stream>>>(x, wr, wd, qkv);
  k_qk_softmax<<<dim3(64, 64), 256, 0, stream>>>(qkv, attn);
  k_av<<<dim3(64, 16), 256, 0, stream>>>(attn, qkv, OX);
  k_uo<<<dim3(64, 8), 256, 0, stream>>>(attn, OX, U);
  k_combine<<<16384, 256, 0, stream>>>(OX, U, out);
}

// Round 2
// 201.623 us; speedup vs baseline: 2.0624x; 2.0624x over previous
//
#include <hip/hip_runtime.h>
#include <cstdint>
#include <cstddef>

// ---------------------------------------------------------------------------
// B=4, N=1024, C=256, H=8, hd=32, ALPHA=0.6
// softmax rows sum to 1 => S_x = attn_x^T; associativity kills the N^3 work:
//   out_rd = a*attn_r^T@(attn_d@vd) + (1-a)*(attn_r@vd + attn_d@vd), sym. dr.
// f16 MFMA pipeline:
//   K1 proj (fp32 vector): qkvh f16 [8192][768] (q,k cols) + VT f16 [bh][64][1024]
//   K2 qk+softmax (MFMA 16x16x32_f16, K=hd=32 -> 1 mfma per frag): attn f16
//   K3 av (MFMA): OX f32 [bb][1024][64] + OT f16 [bb][64][1024]
//   K4 uo (MFMA): U f32 [pb][32][1024]   (B operand gathered 2B from attn)
//   K5 combine: 4 outputs
// ---------------------------------------------------------------------------

typedef _Float16 f16;
typedef _Float16 half8 __attribute__((ext_vector_type(8)));
typedef float f32x4 __attribute__((ext_vector_type(4)));

#define ALPHA_F 0.6f
#define OMA_F   0.4f
#define SCALE_F 0.17677669529663687f  // 1/sqrt(32)

static const size_t WS_QKVH = 0;               // 8192*768*2      = 12,582,912
static const size_t WS_VT   = 12582912ull;     // 32*64*1024*2    =  4,194,304
static const size_t WS_ATTN = 16777216ull;     // 64*1024*1024*2  = 134,217,728
static const size_t WS_OX   = 150994944ull;    // 64*1024*64*4    = 16,777,216
static const size_t WS_OT   = 167772160ull;    // 64*64*1024*2    =  8,388,608
static const size_t WS_U    = 176160768ull;    // 64*32*1024*4    =  8,388,608
// total 184,549,376 B (== round-0 footprint)

// ---------------------------------------------------------------------------
// K1: projection GEMM (fp32).  M=8192, N=768, K=256.
// j0<512: write f16 qkvh rows.  j0>=512: LDS-transpose, write VT[bh][j][m].
__global__ __launch_bounds__(256) void k_proj(const float* __restrict__ x,
                                              const float* __restrict__ wr,
                                              const float* __restrict__ wd,
                                              f16* __restrict__ qkvh,
                                              f16* __restrict__ VT) {
  __shared__ float As[32][68];
  __shared__ float Bs[32][68];
  __shared__ f16 vs[64][72];
  const int t  = threadIdx.x;
  const int m0 = blockIdx.x * 64;
  const int j0 = blockIdx.y * 64;
  const int br = m0 >> 12;
  const float* w = br ? wd : wr;
  const int bn0 = m0 & 4095;
  const int tx = t & 15, ty = t >> 4;
  const int lr = t >> 2;
  const int lk = (t & 3) * 8;
  const float* xbase = x + (size_t)(bn0 + lr) * 512 + br * 256 + lk;
  const float* wbase = w + (size_t)(j0 + lr) * 256 + lk;
  float acc[4][4] = {};
  for (int k0 = 0; k0 < 256; k0 += 32) {
    float4 a0 = *(const float4*)(xbase + k0);
    float4 a1 = *(const float4*)(xbase + k0 + 4);
    float4 b0 = *(const float4*)(wbase + k0);
    float4 b1 = *(const float4*)(wbase + k0 + 4);
    __syncthreads();
    As[lk + 0][lr] = a0.x; As[lk + 1][lr] = a0.y; As[lk + 2][lr] = a0.z; As[lk + 3][lr] = a0.w;
    As[lk + 4][lr] = a1.x; As[lk + 5][lr] = a1.y; As[lk + 6][lr] = a1.z; As[lk + 7][lr] = a1.w;
    Bs[lk + 0][lr] = b0.x; Bs[lk + 1][lr] = b0.y; Bs[lk + 2][lr] = b0.z; Bs[lk + 3][lr] = b0.w;
    Bs[lk + 4][lr] = b1.x; Bs[lk + 5][lr] = b1.y; Bs[lk + 6][lr] = b1.z; Bs[lk + 7][lr] = b1.w;
    __syncthreads();
#pragma unroll
    for (int kk = 0; kk < 32; ++kk) {
      float4 a = *(const float4*)&As[kk][ty * 4];
      float4 b = *(const float4*)&Bs[kk][tx * 4];
      acc[0][0] += a.x * b.x; acc[0][1] += a.x * b.y; acc[0][2] += a.x * b.z; acc[0][3] += a.x * b.w;
      acc[1][0] += a.y * b.x; acc[1][1] += a.y * b.y; acc[1][2] += a.y * b.z; acc[1][3] += a.y * b.w;
      acc[2][0] += a.z * b.x; acc[2][1] += a.z * b.y; acc[2][2] += a.z * b.z; acc[2][3] += a.z * b.w;
      acc[3][0] += a.w * b.x; acc[3][1] += a.w * b.y; acc[3][2] += a.w * b.z; acc[3][3] += a.w * b.w;
    }
  }
  if (j0 < 512) {
#pragma unroll
    for (int i = 0; i < 4; ++i) {
      union { f16 h[4]; uint2 u; } pk;
#pragma unroll
      for (int cc = 0; cc < 4; ++cc) pk.h[cc] = (f16)acc[i][cc];
      *(uint2*)(qkvh + (size_t)(m0 + ty * 4 + i) * 768 + j0 + tx * 4) = pk.u;
    }
  } else {
#pragma unroll
    for (int i = 0; i < 4; ++i)
#pragma unroll
      for (int cc = 0; cc < 4; ++cc)
        vs[tx * 4 + cc][ty * 4 + i] = (f16)acc[i][cc];
    __syncthreads();
    const int b  = bn0 >> 10;
    const int nn0 = bn0 & 1023;
    const int jl = t >> 2, chunk = (t & 3) * 16;
    const int j  = j0 + jl - 512;
    const int hh = j >> 5, dd = j & 31;
    f16* dst = VT + ((size_t)(b * 8 + hh) * 64 + br * 32 + dd) * 1024 + nn0 + chunk;
    *(uint4*)(dst)     = *(const uint4*)&vs[jl][chunk];
    *(uint4*)(dst + 8) = *(const uint4*)&vs[jl][chunk + 8];
  }
}

// ---------------------------------------------------------------------------
// K2: QK^T (MFMA) + softmax, f16 attn out.
// Block: 512 thr = 8 waves = 2 row-groups x 4 col-stripes; 32 q rows x 1024 m.
__global__ __launch_bounds__(512) void k_qk2(const f16* __restrict__ qkvh,
                                             f16* __restrict__ attn) {
  const int t = threadIdx.x;
  const int bb = blockIdx.x;            // br*32 + bh
  const int br = bb >> 5, bh = bb & 31, b = bh >> 3, h = bh & 7;
  const int q0 = blockIdx.y * 32;
  const int w = t >> 6, rg = w >> 2, cs = w & 3;
  const int l = t & 63, g = l >> 4, li = l & 15;
  const size_t rowbase = (size_t)(br * 4096 + b * 1024) * 768;
  // A fragment: Q rows q0+rg*16+li, k = 8g+jj
  half8 aq = *(const half8*)(qkvh + rowbase + (size_t)(q0 + rg * 16 + li) * 768 + h * 32 + 8 * g);
  const f16* kbase = qkvh + rowbase + 256 + h * 32 + 8 * g;
  f32x4 c[16];
  const f32x4 z = {0.f, 0.f, 0.f, 0.f};
#pragma unroll
  for (int ct = 0; ct < 16; ++ct) {
    const int m = cs * 256 + ct * 16 + li;
    half8 bk = *(const half8*)(kbase + (size_t)m * 768);
    c[ct] = __builtin_amdgcn_mfma_f32_16x16x32_f16(aq, bk, z, 0, 0, 0);
  }
  float s[4] = {0.f, 0.f, 0.f, 0.f};
#pragma unroll
  for (int ct = 0; ct < 16; ++ct)
#pragma unroll
    for (int r = 0; r < 4; ++r) {
      float p = __expf(c[ct][r] * SCALE_F);
      c[ct][r] = p;
      s[r] += p;
    }
#pragma unroll
  for (int r = 0; r < 4; ++r)
#pragma unroll
    for (int xm = 1; xm < 16; xm <<= 1) s[r] += __shfl_xor(s[r], xm, 64);
  __shared__ float red[2][4][16];
  if (li == 0) {
#pragma unroll
    for (int r = 0; r < 4; ++r) red[rg][cs][g * 4 + r] = s[r];
  }
  __syncthreads();
  float rinv[4];
#pragma unroll
  for (int r = 0; r < 4; ++r)
    rinv[r] = 1.0f / (red[rg][0][g * 4 + r] + red[rg][1][g * 4 + r] +
                      red[rg][2][g * 4 + r] + red[rg][3][g * 4 + r]);
  f16* arow = attn + ((size_t)bb * 1024 + q0 + rg * 16) * 1024 + cs * 256 + li;
#pragma unroll
  for (int ct = 0; ct < 16; ++ct)
#pragma unroll
    for (int r = 0; r < 4; ++r)
      arow[(size_t)(g * 4 + r) * 1024 + ct * 16] = (f16)(c[ct][r] * rinv[r]);
}

// ---------------------------------------------------------------------------
// K3: OX[bb] = attn_bb @ [vr|vd]  (MFMA).  Block 256 thr: 128 n x 64 j.
__global__ __launch_bounds__(256) void k_av2(const f16* __restrict__ attn,
                                             const f16* __restrict__ VT,
                                             float* __restrict__ OX,
                                             f16* __restrict__ OT) {
  __shared__ f16 ot[64][136];
  const int t = threadIdx.x;
  const int w = t >> 6, l = t & 63, g = l >> 4, li = l & 15;
  const int bb = blockIdx.x, bh = bb & 31;
  const int n0 = blockIdx.y * 128;
  const f16* a0 = attn + ((size_t)bb << 20) + (size_t)(n0 + w * 32 + li) * 1024 + 8 * g;
  const f16* a1 = a0 + (size_t)16 * 1024;
  const f16* vtb = VT + ((size_t)bh * 64 + li) * 1024 + 8 * g;
  f32x4 c[2][4];
#pragma unroll
  for (int fr = 0; fr < 2; ++fr)
#pragma unroll
    for (int fc = 0; fc < 4; ++fc) c[fr][fc] = (f32x4){0.f, 0.f, 0.f, 0.f};
  for (int m0 = 0; m0 < 1024; m0 += 32) {
    half8 A0 = *(const half8*)(a0 + m0);
    half8 A1 = *(const half8*)(a1 + m0);
#pragma unroll
    for (int fc = 0; fc < 4; ++fc) {
      half8 B = *(const half8*)(vtb + (size_t)(fc * 16) * 1024 + m0);
      c[0][fc] = __builtin_amdgcn_mfma_f32_16x16x32_f16(A0, B, c[0][fc], 0, 0, 0);
      c[1][fc] = __builtin_amdgcn_mfma_f32_16x16x32_f16(A1, B, c[1][fc], 0, 0, 0);
    }
  }
#pragma unroll
  for (int fr = 0; fr < 2; ++fr)
#pragma unroll
    for (int fc = 0; fc < 4; ++fc)
#pragma unroll
      for (int r = 0; r < 4; ++r) {
        const int n = n0 + w * 32 + fr * 16 + g * 4 + r;
        OX[((size_t)bb * 1024 + n) * 64 + fc * 16 + li] = c[fr][fc][r];
        ot[fc * 16 + li][w * 32 + fr * 16 + g * 4 + r] = (f16)c[fr][fc][r];
      }
  __syncthreads();
  const int jl = t >> 2, chunk = (t & 3) * 32;
  f16* dst = OT + ((size_t)bb * 64 + jl) * 1024 + n0 + chunk;
#pragma unroll
  for (int k = 0; k < 4; ++k)
    *(uint4*)(dst + k * 8) = *(const uint4*)&ot[jl][chunk + k * 8];
}

// ---------------------------------------------------------------------------
// K4: U[pb][d][n] = sum_q O[q][d]*attn[q][n]  (MFMA; B gathered 2B loads).
// Block 256 thr: 32 d x 128 n (wave: 32 d x 32 n).
__global__ __launch_bounds__(256) void k_uo2(const f16* __restrict__ attn,
                                             const f16* __restrict__ OT,
                                             float* __restrict__ U) {
  const int t = threadIdx.x;
  const int w = t >> 6, l = t & 63, g = l >> 4, li = l & 15;
  const int pb = blockIdx.x, p = pb >> 5, bh = pb & 31;
  const int n0 = blockIdx.y * 128 + w * 32;
  const int obb  = p ? bh : 32 + bh;
  const int joff = p ? 0 : 32;
  const int abb  = p ? 32 + bh : bh;
  const f16* ap0 = OT + ((size_t)obb * 64 + joff + li) * 1024 + 8 * g;
  const f16* ap1 = ap0 + (size_t)16 * 1024;
  const f16* bp = attn + ((size_t)abb << 20) + (size_t)(8 * g) * 1024 + n0 + li;
  f32x4 c[2][2];
#pragma unroll
  for (int fr = 0; fr < 2; ++fr)
#pragma unroll
    for (int fc = 0; fc < 2; ++fc) c[fr][fc] = (f32x4){0.f, 0.f, 0.f, 0.f};
  for (int q0 = 0; q0 < 1024; q0 += 32) {
    half8 A0 = *(const half8*)(ap0 + q0);
    half8 A1 = *(const half8*)(ap1 + q0);
#pragma unroll
    for (int fc = 0; fc < 2; ++fc) {
      const f16* bq = bp + (size_t)q0 * 1024 + fc * 16;
      half8 B;
#pragma unroll
      for (int jj = 0; jj < 8; ++jj) B[jj] = bq[(size_t)jj * 1024];
      c[0][fc] = __builtin_amdgcn_mfma_f32_16x16x32_f16(A0, B, c[0][fc], 0, 0, 0);
      c[1][fc] = __builtin_amdgcn_mfma_f32_16x16x32_f16(A1, B, c[1][fc], 0, 0, 0);
    }
  }
#pragma unroll
  for (int fr = 0; fr < 2; ++fr)
#pragma unroll
    for (int fc = 0; fc < 2; ++fc)
#pragma unroll
      for (int r = 0; r < 4; ++r)
        U[((size_t)pb * 32 + fr * 16 + g * 4 + r) * 1024 + n0 + fc * 16 + li] = c[fr][fc][r];
}

// ---------------------------------------------------------------------------
// K5: combine + head-interleave.
__global__ __launch_bounds__(256) void k_combine(const float* __restrict__ OX,
                                                 const float* __restrict__ U,
                                                 float* __restrict__ out) {
  const int idx = blockIdx.x;
  const int n = idx & 1023;
  const int ob = idx >> 10;
  const int b = ob & 3, o = ob >> 2;
  const int t = threadIdx.x;
  const int h = t >> 5, d = t & 31;
  const int bh = b * 8 + h;
  const size_t x0 = ((size_t)bh * 1024 + n) * 64;
  const size_t x1 = ((size_t)(32 + bh) * 1024 + n) * 64;
  float r;
  if (o == 0) {
    r = ALPHA_F * U[((size_t)(32 + bh) * 32 + d) * 1024 + n] + OMA_F * (OX[x1 + d] + OX[x0 + d]);
  } else if (o == 1) {
    r = ALPHA_F * U[((size_t)bh * 32 + d) * 1024 + n] + OMA_F * (OX[x0 + 32 + d] + OX[x1 + 32 + d]);
  } else if (o == 2) {
    r = OX[x0 + d];
  } else {
    r = OX[x1 + 32 + d];
  }
  out[((size_t)(o * 4 + b) * 1024 + n) * 256 + t] = r;
}

// ---------------------------------------------------------------------------
extern "C" void kernel_launch(void* const* d_in, const int* in_sizes, int n_in,
                              void* d_out, int out_size, void* d_ws, size_t ws_size,
                              hipStream_t stream) {
  const float* x  = (const float*)d_in[0];
  const float* wr = (const float*)d_in[1];
  const float* wd = (const float*)d_in[2];
  float* out = (float*)d_out;
  char* ws = (char*)d_ws;
  f16* qkvh = (f16*)(ws + WS_QKVH);
  f16* VT   = (f16*)(ws + WS_VT);
  f16* attn = (f16*)(ws + WS_ATTN);
  float* OX = (float*)(ws + WS_OX);
  f16* OT   = (f16*)(ws + WS_OT);
  float* U  = (float*)(ws + WS_U);

  k_proj<<<dim3(128, 12), 256, 0, stream>>>(x, wr, wd, qkvh, VT);
  k_qk2<<<dim3(64, 32), 512, 0, stream>>>(qkvh, attn);
  k_av2<<<dim3(64, 8), 256, 0, stream>>>(attn, VT, OX, OT);
  k_uo2<<<dim3(64, 8), 256, 0, stream>>>(attn, OT, U);
  k_combine<<<16384, 256, 0, stream>>>(OX, U, out);
}

// Round 3
// 200.918 us; speedup vs baseline: 2.0696x; 1.0035x over previous
//
#include <hip/hip_runtime.h>
#include <cstdint>
#include <cstddef>

// ---------------------------------------------------------------------------
// B=4, N=1024, C=256, H=8, hd=32, ALPHA=0.6
// softmax rows sum to 1 => S_x = attn_x^T; associativity kills the N^3 work:
//   out_rd = a*attn_r^T@(attn_d@vd) + (1-a)*(attn_r@vd + attn_d@vd), sym. dr.
// This round: attn is NEVER materialized to HBM.
//   K1 proj (fp32 vector): qkvh f16 [8192][768] + VT f16 [bh][64][1024]
//   K2 fused1: QK^T (MFMA) + softmax (store rinv) + P->LDS + PV (MFMA)
//              -> OT f16 [bb][64][1024], out_r/out_d written directly
//   K3 fused2: recompute attn tiles (MFMA+exp*rinv) -> U = attn^T @ O (MFMA)
//              fused combine -> out_dr/out_rd written directly
// ---------------------------------------------------------------------------

typedef _Float16 f16;
typedef _Float16 half8 __attribute__((ext_vector_type(8)));
typedef float f32x4 __attribute__((ext_vector_type(4)));

#define ALPHA_F 0.6f
#define OMA_F   0.4f
#define SCALE_F 0.17677669529663687f  // 1/sqrt(32)

static const size_t WS_QKVH = 0;               // 8192*768*2   = 12,582,912
static const size_t WS_VT   = 12582912ull;     // 32*64*1024*2 =  4,194,304
static const size_t WS_OT   = 16777216ull;     // 64*64*1024*2 =  8,388,608
static const size_t WS_RS   = 25165824ull;     // 64*1024*4    =    262,144

// ---------------------------------------------------------------------------
// K1: projection GEMM (fp32).  M=8192, N=768, K=256.  (unchanged from r2)
__global__ __launch_bounds__(256) void k_proj(const float* __restrict__ x,
                                              const float* __restrict__ wr,
                                              const float* __restrict__ wd,
                                              f16* __restrict__ qkvh,
                                              f16* __restrict__ VT) {
  __shared__ float As[32][68];
  __shared__ float Bs[32][68];
  __shared__ f16 vs[64][72];
  const int t  = threadIdx.x;
  const int m0 = blockIdx.x * 64;
  const int j0 = blockIdx.y * 64;
  const int br = m0 >> 12;
  const float* w = br ? wd : wr;
  const int bn0 = m0 & 4095;
  const int tx = t & 15, ty = t >> 4;
  const int lr = t >> 2;
  const int lk = (t & 3) * 8;
  const float* xbase = x + (size_t)(bn0 + lr) * 512 + br * 256 + lk;
  const float* wbase = w + (size_t)(j0 + lr) * 256 + lk;
  float acc[4][4] = {};
  for (int k0 = 0; k0 < 256; k0 += 32) {
    float4 a0 = *(const float4*)(xbase + k0);
    float4 a1 = *(const float4*)(xbase + k0 + 4);
    float4 b0 = *(const float4*)(wbase + k0);
    float4 b1 = *(const float4*)(wbase + k0 + 4);
    __syncthreads();
    As[lk + 0][lr] = a0.x; As[lk + 1][lr] = a0.y; As[lk + 2][lr] = a0.z; As[lk + 3][lr] = a0.w;
    As[lk + 4][lr] = a1.x; As[lk + 5][lr] = a1.y; As[lk + 6][lr] = a1.z; As[lk + 7][lr] = a1.w;
    Bs[lk + 0][lr] = b0.x; Bs[lk + 1][lr] = b0.y; Bs[lk + 2][lr] = b0.z; Bs[lk + 3][lr] = b0.w;
    Bs[lk + 4][lr] = b1.x; Bs[lk + 5][lr] = b1.y; Bs[lk + 6][lr] = b1.z; Bs[lk + 7][lr] = b1.w;
    __syncthreads();
#pragma unroll
    for (int kk = 0; kk < 32; ++kk) {
      float4 a = *(const float4*)&As[kk][ty * 4];
      float4 b = *(const float4*)&Bs[kk][tx * 4];
      acc[0][0] += a.x * b.x; acc[0][1] += a.x * b.y; acc[0][2] += a.x * b.z; acc[0][3] += a.x * b.w;
      acc[1][0] += a.y * b.x; acc[1][1] += a.y * b.y; acc[1][2] += a.y * b.z; acc[1][3] += a.y * b.w;
      acc[2][0] += a.z * b.x; acc[2][1] += a.z * b.y; acc[2][2] += a.z * b.z; acc[2][3] += a.z * b.w;
      acc[3][0] += a.w * b.x; acc[3][1] += a.w * b.y; acc[3][2] += a.w * b.z; acc[3][3] += a.w * b.w;
    }
  }
  if (j0 < 512) {
#pragma unroll
    for (int i = 0; i < 4; ++i) {
      union { f16 h[4]; uint2 u; } pk;
#pragma unroll
      for (int cc = 0; cc < 4; ++cc) pk.h[cc] = (f16)acc[i][cc];
      *(uint2*)(qkvh + (size_t)(m0 + ty * 4 + i) * 768 + j0 + tx * 4) = pk.u;
    }
  } else {
#pragma unroll
    for (int i = 0; i < 4; ++i)
#pragma unroll
      for (int cc = 0; cc < 4; ++cc)
        vs[tx * 4 + cc][ty * 4 + i] = (f16)acc[i][cc];
    __syncthreads();
    const int b  = bn0 >> 10;
    const int nn0 = bn0 & 1023;
    const int jl = t >> 2, chunk = (t & 3) * 16;
    const int j  = j0 + jl - 512;
    const int hh = j >> 5, dd = j & 31;
    f16* dst = VT + ((size_t)(b * 8 + hh) * 64 + br * 32 + dd) * 1024 + nn0 + chunk;
    *(uint4*)(dst)     = *(const uint4*)&vs[jl][chunk];
    *(uint4*)(dst + 8) = *(const uint4*)&vs[jl][chunk + 8];
  }
}

// ---------------------------------------------------------------------------
// K2: fused QK^T + softmax + PV.  Block 512 thr = 8 waves, 32 q-rows, bb fixed.
// Stage A wave (rg,cs): rows rg*16..+16, cols cs*256..+256 of S; softmax.
// P staged to LDS in two 512-col halves (f16, [32][520] pad->2-way free).
// Stage B wave (qf,jf): one 16x16 frag of [32 q][64 j], K=512 per half.
__global__ __launch_bounds__(512) void k_fused1(const f16* __restrict__ qkvh,
                                                const f16* __restrict__ VT,
                                                f16* __restrict__ OT,
                                                float* __restrict__ rsums,
                                                float* __restrict__ out) {
  __shared__ f16 Pbuf[32][520];
  __shared__ float red[2][4][16];
  __shared__ float Obuf[32][68];
  const int t = threadIdx.x;
  const int bb = blockIdx.x;            // br*32 + bh
  const int br = bb >> 5, bh = bb & 31, b = bh >> 3, h = bh & 7;
  const int q0 = blockIdx.y * 32;
  const int w = t >> 6, l = t & 63, g = l >> 4, li = l & 15;
  const int rg = w >> 2, cs = w & 3;
  const size_t rowbase = (size_t)(br * 4096 + b * 1024) * 768;
  // ---- stage A: S = QK^T, softmax ----
  half8 aq = *(const half8*)(qkvh + rowbase + (size_t)(q0 + rg * 16 + li) * 768 + h * 32 + 8 * g);
  const f16* kbase = qkvh + rowbase + 256 + h * 32 + 8 * g;
  f32x4 c[16];
  const f32x4 z = {0.f, 0.f, 0.f, 0.f};
#pragma unroll
  for (int ct = 0; ct < 16; ++ct) {
    half8 bk = *(const half8*)(kbase + (size_t)(cs * 256 + ct * 16 + li) * 768);
    c[ct] = __builtin_amdgcn_mfma_f32_16x16x32_f16(aq, bk, z, 0, 0, 0);
  }
  float s[4] = {0.f, 0.f, 0.f, 0.f};
#pragma unroll
  for (int ct = 0; ct < 16; ++ct)
#pragma unroll
    for (int r = 0; r < 4; ++r) {
      float p = __expf(c[ct][r] * SCALE_F);
      c[ct][r] = p;
      s[r] += p;
    }
#pragma unroll
  for (int r = 0; r < 4; ++r)
#pragma unroll
    for (int xm = 1; xm < 16; xm <<= 1) s[r] += __shfl_xor(s[r], xm, 64);
  if (li == 0) {
#pragma unroll
    for (int r = 0; r < 4; ++r) red[rg][cs][g * 4 + r] = s[r];
  }
  __syncthreads();
  float rinv[4];
#pragma unroll
  for (int r = 0; r < 4; ++r)
    rinv[r] = 1.0f / (red[rg][0][g * 4 + r] + red[rg][1][g * 4 + r] +
                      red[rg][2][g * 4 + r] + red[rg][3][g * 4 + r]);
#pragma unroll
  for (int ct = 0; ct < 16; ++ct)
#pragma unroll
    for (int r = 0; r < 4; ++r) c[ct][r] *= rinv[r];
  if (cs == 0 && li == 0) {
#pragma unroll
    for (int r = 0; r < 4; ++r)
      rsums[(size_t)bb * 1024 + q0 + rg * 16 + 4 * g + r] = rinv[r];
  }
  // ---- stage B: OX = P @ [vr|vd], two 512-col halves through LDS ----
  const int qf = w >> 2, jf = w & 3;
  const f16* vtb = VT + ((size_t)bh * 64 + jf * 16 + li) * 1024 + 8 * g;
  f32x4 acc = z;
#pragma unroll
  for (int half = 0; half < 2; ++half) {
    if (half) __syncthreads();  // protect previous half's reads
    if ((cs >> 1) == half) {
#pragma unroll
      for (int ct = 0; ct < 16; ++ct)
#pragma unroll
        for (int r = 0; r < 4; ++r)
          Pbuf[rg * 16 + 4 * g + r][(cs & 1) * 256 + ct * 16 + li] = (f16)c[ct][r];
    }
    __syncthreads();
    for (int m0 = 0; m0 < 512; m0 += 32) {
      half8 A = *(const half8*)&Pbuf[qf * 16 + li][m0 + 8 * g];
      half8 B = *(const half8*)(vtb + half * 512 + m0);
      acc = __builtin_amdgcn_mfma_f32_16x16x32_f16(A, B, acc, 0, 0, 0);
    }
  }
  __syncthreads();
#pragma unroll
  for (int r = 0; r < 4; ++r) Obuf[qf * 16 + 4 * g + r][jf * 16 + li] = acc[r];
  __syncthreads();
  // ---- epilogue: OT (f16, [bb][j][n]) + out_r / out_d ----
  {
    const int j = t >> 3, nn = (t & 7) * 4;
    union { f16 h[4]; uint2 u; } pk;
#pragma unroll
    for (int i = 0; i < 4; ++i) pk.h[i] = (f16)Obuf[nn + i][j];
    *(uint2*)(OT + ((size_t)bb * 64 + j) * 1024 + q0 + nn) = pk.u;
  }
  if (t < 256) {
    const int n = t >> 3, jj = (t & 7) * 4;
    const int o = 2 + br;  // out_r (o=2) from j 0:32, out_d (o=3) from j 32:64
    float4 v = *(const float4*)&Obuf[n][br * 32 + jj];
    *(float4*)(out + ((size_t)(o * 4 + b) * 1024 + q0 + n) * 256 + h * 32 + jj) = v;
  }
}

// ---------------------------------------------------------------------------
// K3: fused recompute + U = attn^T @ O + combine.
// Block 512 thr = 8 waves; (pb = p*32+bh, n-tile 128).  Wave w owns n-frag w.
// Per 32-row k-chunk: S'' = mfma(Q,K) -> exp*rinv -> f16 LDS (double buf)
//                     -> 2 U-MFMAs (df=0,1) with A = OT rows.
__global__ __launch_bounds__(512) void k_fused2(const f16* __restrict__ qkvh,
                                                const f16* __restrict__ OT,
                                                const float* __restrict__ rsums,
                                                float* __restrict__ out) {
  __shared__ f16 Pb[2][128][40];
  __shared__ float Ub[32][133];
  __shared__ float rbuf[1024];
  const int t = threadIdx.x;
  const int pb = blockIdx.x;            // p*32 + bh
  const int p = pb >> 5, bh = pb & 31, b = bh >> 3, h = bh & 7;
  const int n0 = blockIdx.y * 128;
  const int w = t >> 6, l = t & 63, g = l >> 4, li = l & 15;
  const int abb  = p * 32 + bh;         // attn branch (p=0: r, p=1: d)
  const int obb  = p ? bh : 32 + bh;    // O operand bb
  const int aoff = p ? 0 : 32;          // col offset within OT rows
  const size_t rowbase = (size_t)(p * 4096 + b * 1024) * 768;
  rbuf[t]       = rsums[(size_t)abb * 1024 + t];
  rbuf[t + 512] = rsums[(size_t)abb * 1024 + t + 512];
  // K fragment (B for S''): rows n0 + w*16 + li  (held in regs for all chunks)
  half8 kfrag = *(const half8*)(qkvh + rowbase + (size_t)(n0 + w * 16 + li) * 768 + 256 + h * 32 + 8 * g);
  const f16* otb = OT + ((size_t)obb * 64 + aoff + li) * 1024 + 8 * g;
  const f32x4 z = {0.f, 0.f, 0.f, 0.f};
  f32x4 u0 = z, u1 = z;
  __syncthreads();
  for (int k0 = 0; k0 < 1024; k0 += 32) {
    f16 (*pb_)[40] = Pb[(k0 >> 5) & 1];
    half8 qa0 = *(const half8*)(qkvh + rowbase + (size_t)(k0 + li) * 768 + h * 32 + 8 * g);
    half8 qa1 = *(const half8*)(qkvh + rowbase + (size_t)(k0 + 16 + li) * 768 + h * 32 + 8 * g);
    f32x4 s0 = __builtin_amdgcn_mfma_f32_16x16x32_f16(qa0, kfrag, z, 0, 0, 0);
    f32x4 s1 = __builtin_amdgcn_mfma_f32_16x16x32_f16(qa1, kfrag, z, 0, 0, 0);
    union { f16 h[4]; uint2 u; } p0, p1;
#pragma unroll
    for (int r = 0; r < 4; ++r) {
      p0.h[r] = (f16)(__expf(s0[r] * SCALE_F) * rbuf[k0 + 4 * g + r]);
      p1.h[r] = (f16)(__expf(s1[r] * SCALE_F) * rbuf[k0 + 16 + 4 * g + r]);
    }
    *(uint2*)&pb_[w * 16 + li][4 * g]      = p0.u;
    *(uint2*)&pb_[w * 16 + li][16 + 4 * g] = p1.u;
    __syncthreads();
    half8 A0 = *(const half8*)(otb + k0);
    half8 A1 = *(const half8*)(otb + (size_t)16 * 1024 + k0);
    half8 B  = *(const half8*)&pb_[w * 16 + li][8 * g];
    u0 = __builtin_amdgcn_mfma_f32_16x16x32_f16(A0, B, u0, 0, 0, 0);
    u1 = __builtin_amdgcn_mfma_f32_16x16x32_f16(A1, B, u1, 0, 0, 0);
  }
  // ---- combine: alpha*U + 0.4*(OT_r + OT_d) -> Ub ----
#pragma unroll
  for (int df = 0; df < 2; ++df) {
#pragma unroll
    for (int r = 0; r < 4; ++r) {
      const int drow = aoff + df * 16 + 4 * g + r;
      const int n = n0 + w * 16 + li;
      float uu = df ? u1[r] : u0[r];
      float a1 = (float)OT[((size_t)bh * 64 + drow) * 1024 + n];
      float a2 = (float)OT[((size_t)(32 + bh) * 64 + drow) * 1024 + n];
      Ub[df * 16 + 4 * g + r][w * 16 + li] = ALPHA_F * uu + OMA_F * (a1 + a2);
    }
  }
  __syncthreads();
  // ---- transpose-write out rows ----
  {
    const int n = t >> 2, dq = (t & 3) * 8;
    const int o = 1 - p;  // p=0 -> out_rd (o=1), p=1 -> out_dr (o=0)
    float v[8];
#pragma unroll
    for (int j = 0; j < 8; ++j) v[j] = Ub[dq + j][n];
    float* dst = out + ((size_t)(o * 4 + b) * 1024 + n0 + n) * 256 + h * 32 + dq;
    float4 v0 = make_float4(v[0], v[1], v[2], v[3]);
    float4 v1 = make_float4(v[4], v[5], v[6], v[7]);
    *(float4*)dst = v0;
    *(float4*)(dst + 4) = v1;
  }
}

// ---------------------------------------------------------------------------
extern "C" void kernel_launch(void* const* d_in, const int* in_sizes, int n_in,
                              void* d_out, int out_size, void* d_ws, size_t ws_size,
                              hipStream_t stream) {
  const float* x  = (const float*)d_in[0];
  const float* wr = (const float*)d_in[1];
  const float* wd = (const float*)d_in[2];
  float* out = (float*)d_out;
  char* ws = (char*)d_ws;
  f16* qkvh   = (f16*)(ws + WS_QKVH);
  f16* VT     = (f16*)(ws + WS_VT);
  f16* OT     = (f16*)(ws + WS_OT);
  float* rsums = (float*)(ws + WS_RS);

  k_proj<<<dim3(128, 12), 256, 0, stream>>>(x, wr, wd, qkvh, VT);
  k_fused1<<<dim3(64, 32), 512, 0, stream>>>(qkvh, VT, OT, rsums, out);
  k_fused2<<<dim3(64, 8), 512, 0, stream>>>(qkvh, OT, rsums, out);
}

// Round 5
// 191.740 us; speedup vs baseline: 2.1687x; 1.0479x over previous
//
#include <hip/hip_runtime.h>
#include <cstdint>
#include <cstddef>

// ---------------------------------------------------------------------------
// B=4, N=1024, C=256, H=8, hd=32, ALPHA=0.6
// softmax rows sum to 1 => S_x = attn_x^T; associativity kills the N^3 work.
// All-MFMA, barrier-free main loops. Key trick: compute transposed products
// (mfma(K,Q), mfma(W,X)) so each lane's 4 acc values are contraction-
// consecutive -> pack to ds_write_b64, read back as A/B frags via b128.
//   K0 cast:   x,w -> f16 (xh [2][4096][256], wh [2][768][256])
//   K1 projm:  MFMA GEMM -> qkvh f16 [8192][768]; v-cols -> VT [bh][64][1024]
//   K2 fused1: S^T=mfma(K,Q) -> exp (unnorm) -> P(LDS,per-wave) -> PV MFMA
//              -> OT f16 [bb][64][1024], rsums; out_r/out_d written straight
//              from the o[] registers (no LDS readback -- r4 bug was there)
//   K3 fused2: recompute S -> exp*rinv -> P(LDS) -> U=mfma(OT,P) -> combine
//              -> out_dr/out_rd
// ---------------------------------------------------------------------------

typedef _Float16 f16;
typedef _Float16 half8 __attribute__((ext_vector_type(8)));
typedef float f32x4 __attribute__((ext_vector_type(4)));

#define ALPHA_F 0.6f
#define OMA_F   0.4f
#define SCALE_F 0.17677669529663687f  // 1/sqrt(32)

static const size_t WS_XH   = 0;            //  4,194,304
static const size_t WS_WH   = 4194304ull;   //    786,432
static const size_t WS_QKVH = 4980736ull;   // 12,582,912
static const size_t WS_VT   = 17563648ull;  //  4,194,304
static const size_t WS_OT   = 21757952ull;  //  8,388,608
static const size_t WS_RS   = 30146560ull;  //    262,144

// ---------------------------------------------------------------------------
// K0: cast x -> xh[2][4096][256], w_r/w_d -> wh[2][768][256].  8 f16/thread.
__global__ __launch_bounds__(256) void k_cast(const float* __restrict__ x,
                                              const float* __restrict__ wr,
                                              const float* __restrict__ wd,
                                              f16* __restrict__ xh,
                                              f16* __restrict__ wh) {
  const int gid = blockIdx.x * 256 + threadIdx.x;
  if (gid < 262144) {
    const int i0 = gid * 8;
    const int k = i0 & 255, row = (i0 >> 8) & 4095, br = i0 >> 20;
    const float* src = x + (size_t)row * 512 + br * 256 + k;
    float4 a = *(const float4*)src;
    float4 b = *(const float4*)(src + 4);
    union { f16 h[8]; uint4 u; } pk;
    pk.h[0] = (f16)a.x; pk.h[1] = (f16)a.y; pk.h[2] = (f16)a.z; pk.h[3] = (f16)a.w;
    pk.h[4] = (f16)b.x; pk.h[5] = (f16)b.y; pk.h[6] = (f16)b.z; pk.h[7] = (f16)b.w;
    *(uint4*)(xh + i0) = pk.u;
  } else {
    const int i0 = (gid - 262144) * 8;
    const int br = (i0 >= 196608) ? 1 : 0;
    const int j = i0 - br * 196608;
    const float* w = br ? wd : wr;
    float4 a = *(const float4*)(w + j);
    float4 b = *(const float4*)(w + j + 4);
    union { f16 h[8]; uint4 u; } pk;
    pk.h[0] = (f16)a.x; pk.h[1] = (f16)a.y; pk.h[2] = (f16)a.z; pk.h[3] = (f16)a.w;
    pk.h[4] = (f16)b.x; pk.h[5] = (f16)b.y; pk.h[6] = (f16)b.z; pk.h[7] = (f16)b.w;
    *(uint4*)(wh + i0) = pk.u;
  }
}

// ---------------------------------------------------------------------------
// K1: proj MFMA GEMM.  Block 512thr=8 waves; m-tile 128 (wave:16), j-tile 64.
// qk cols (j0<512): C[j][n]=mfma(W,X) -> pack b64 [n][j] -> qkvh rows.
// v cols (j0>=512): C[n][j]=mfma(X,W) -> pack b64 [j][n] -> VT rows.
__global__ __launch_bounds__(512) void k_projm(const f16* __restrict__ xh,
                                               const f16* __restrict__ wh,
                                               f16* __restrict__ qkvh,
                                               f16* __restrict__ VT) {
  __shared__ f16 sc[8][64][24];
  const int t = threadIdx.x;
  const int w = t >> 6, l = t & 63, g = l >> 4, li = l & 15;
  const int m0 = blockIdx.x * 128;
  const int j0 = blockIdx.y * 64;
  const int br = m0 >> 12;
  const int mrow = m0 & 4095;
  const f16* xrow = xh + (size_t)(br * 4096 + mrow + w * 16 + li) * 256;
  const f16* wr0 = wh + (size_t)(br * 768 + j0 + li) * 256;
  const f32x4 z = {0.f, 0.f, 0.f, 0.f};
  f32x4 c[4] = {z, z, z, z};
  const bool qk = (j0 < 512);
#pragma unroll
  for (int kk = 0; kk < 8; ++kk) {
    half8 xa = *(const half8*)(xrow + kk * 32 + 8 * g);
#pragma unroll
    for (int jf = 0; jf < 4; ++jf) {
      half8 wa = *(const half8*)(wr0 + (size_t)(jf * 16) * 256 + kk * 32 + 8 * g);
      if (qk) c[jf] = __builtin_amdgcn_mfma_f32_16x16x32_f16(wa, xa, c[jf], 0, 0, 0);
      else    c[jf] = __builtin_amdgcn_mfma_f32_16x16x32_f16(xa, wa, c[jf], 0, 0, 0);
    }
  }
  if (qk) {
    // C[j][n]: col n=li, rows j=j0+jf*16+4g+r  -> Qw[n][j] rows [16][72]
    f16 (*Qw)[72] = (f16(*)[72])&sc[w][0][0];
#pragma unroll
    for (int jf = 0; jf < 4; ++jf) {
      union { f16 h[4]; uint2 u; } pk;
#pragma unroll
      for (int r = 0; r < 4; ++r) pk.h[r] = (f16)c[jf][r];
      *(uint2*)&Qw[li][jf * 16 + 4 * g] = pk.u;
    }
    const int n = l >> 2, jc = (l & 3) * 16;
    uint4 v0 = *(const uint4*)&Qw[n][jc];
    uint4 v1 = *(const uint4*)&Qw[n][jc + 8];
    f16* dst = qkvh + (size_t)(m0 + w * 16 + n) * 768 + j0 + jc;
    *(uint4*)dst = v0;
    *(uint4*)(dst + 8) = v1;
  } else {
    // C[n][j]: col j=j0+jf*16+li, rows n=4g+r -> Vw[j][n] rows [64][24]
    f16 (*Vw)[24] = (f16(*)[24])&sc[w][0][0];
#pragma unroll
    for (int jf = 0; jf < 4; ++jf) {
      union { f16 h[4]; uint2 u; } pk;
#pragma unroll
      for (int r = 0; r < 4; ++r) pk.h[r] = (f16)c[jf][r];
      *(uint2*)&Vw[jf * 16 + li][4 * g] = pk.u;
    }
    const int jg = j0 + l - 512;
    const int hh = jg >> 5, dd = jg & 31;
    const int b = mrow >> 10;
    const int nn = (mrow & 1023) + w * 16;
    uint4 v0 = *(const uint4*)&Vw[l][0];
    uint4 v1 = *(const uint4*)&Vw[l][8];
    f16* dst = VT + ((size_t)(b * 8 + hh) * 64 + br * 32 + dd) * 1024 + nn;
    *(uint4*)dst = v0;
    *(uint4*)(dst + 8) = v1;
  }
}

// ---------------------------------------------------------------------------
// K2: fused flash pass. Block 512=8 waves, each wave owns 16 q-rows. No
// barriers: P is per-wave LDS. S^T=mfma(K,Q) -> b64 pack -> b128 A-frag.
// out_r/out_d written straight from o[] registers (f32) -- no LDS readback.
__global__ __launch_bounds__(512) void k_fused1(const f16* __restrict__ qkvh,
                                                const f16* __restrict__ VT,
                                                f16* __restrict__ OT,
                                                float* __restrict__ rsums,
                                                float* __restrict__ out) {
  __shared__ f16 scw[8][1536];
  __shared__ float rsh[8][16];
  const int t = threadIdx.x;
  const int bb = blockIdx.x;
  const int br = bb >> 5, bh = bb & 31, b = bh >> 3, h = bh & 7;
  const int w = t >> 6, l = t & 63, g = l >> 4, li = l & 15;
  const int q0 = blockIdx.y * 128 + w * 16;
  const size_t rowbase = (size_t)(br * 4096 + b * 1024) * 768;
  // Q B-frag (col q=li): row q0+li, k=d
  half8 qf = *(const half8*)(qkvh + rowbase + (size_t)(q0 + li) * 768 + h * 32 + 8 * g);
  const f16* kb = qkvh + rowbase + 256 + h * 32 + 8 * g;
  const f16* vb = VT + ((size_t)bh * 64 + li) * 1024 + 8 * g;
  f16 (*P)[72] = (f16(*)[72])&scw[w][0];
  const f32x4 z = {0.f, 0.f, 0.f, 0.f};
  f32x4 o[4] = {z, z, z, z};
  float qsum = 0.f;
  for (int m0 = 0; m0 < 1024; m0 += 64) {
    f32x4 sct[4];
#pragma unroll
    for (int ct = 0; ct < 4; ++ct) {
      half8 ka = *(const half8*)(kb + (size_t)(m0 + ct * 16 + li) * 768);
      sct[ct] = __builtin_amdgcn_mfma_f32_16x16x32_f16(ka, qf, z, 0, 0, 0);
    }
#pragma unroll
    for (int ct = 0; ct < 4; ++ct) {
      union { f16 h[4]; uint2 u; } pk;
#pragma unroll
      for (int r = 0; r < 4; ++r) {
        float p = __expf(sct[ct][r] * SCALE_F);
        qsum += p;
        pk.h[r] = (f16)p;
      }
      *(uint2*)&P[li][ct * 16 + 4 * g] = pk.u;
    }
#pragma unroll
    for (int kk = 0; kk < 2; ++kk) {
      half8 pa = *(const half8*)&P[li][kk * 32 + 8 * g];
#pragma unroll
      for (int jf = 0; jf < 4; ++jf) {
        half8 vv = *(const half8*)(vb + (size_t)(jf * 16) * 1024 + m0 + kk * 32);
        o[jf] = __builtin_amdgcn_mfma_f32_16x16x32_f16(pa, vv, o[jf], 0, 0, 0);
      }
    }
  }
  qsum += __shfl_xor(qsum, 16, 64);
  qsum += __shfl_xor(qsum, 32, 64);
  const float rinv = 1.0f / qsum;
  if (l < 16) {
    rsh[w][li] = rinv;
    rsums[(size_t)bb * 1024 + q0 + li] = rinv;
  }
  float rv[4];
#pragma unroll
  for (int r = 0; r < 4; ++r) rv[r] = rsh[w][4 * g + r];
#pragma unroll
  for (int jf = 0; jf < 4; ++jf)
#pragma unroll
    for (int r = 0; r < 4; ++r) o[jf][r] *= rv[r];
  // ---- out_r (br=0) / out_d (br=1) straight from registers ----
  // o[jf][r] = O[q = 4g+r][j = jf*16+li], rinv-applied, f32.
  // br=0 needs j 0..31 (jf 0,1) -> o=2; br=1 needs j 32..63 (jf 2,3) -> o=3.
  {
    const int jf0 = br * 2;
    float* obase = out + ((size_t)((2 + br) * 4 + b) * 1024 + q0 + 4 * g) * 256 + h * 32 + li;
#pragma unroll
    for (int jf2 = 0; jf2 < 2; ++jf2)
#pragma unroll
      for (int r = 0; r < 4; ++r)
        obase[(size_t)r * 256 + jf2 * 16] = o[jf0 + jf2][r];
  }
  // ---- transpose O (16q x 64j) -> Ow[j][q] rows [64][24], then OT ----
  f16 (*Ow)[24] = (f16(*)[24])&scw[w][0];
#pragma unroll
  for (int jf = 0; jf < 4; ++jf)
#pragma unroll
    for (int rp = 0; rp < 2; ++rp) {
      union { f16 h[2]; unsigned int u; } pk2;
      pk2.h[0] = (f16)o[jf][2 * rp];
      pk2.h[1] = (f16)o[jf][2 * rp + 1];
      *(unsigned int*)&Ow[jf * 16 + li][4 * g + 2 * rp] = pk2.u;
    }
  // OT rows: lane l -> j=l, 16 q's
  {
    uint4 v0 = *(const uint4*)&Ow[l][0];
    uint4 v1 = *(const uint4*)&Ow[l][8];
    f16* dst = OT + ((size_t)bb * 64 + l) * 1024 + q0;
    *(uint4*)dst = v0;
    *(uint4*)(dst + 8) = v1;
  }
}

// ---------------------------------------------------------------------------
// K3: fused recompute + U + combine.  Block 512=8 waves, wave owns 16 n-cols.
// Barrier only for rsums staging.  P per-wave LDS, same b64/b128 trick.
__global__ __launch_bounds__(512) void k_fused2(const f16* __restrict__ qkvh,
                                                const f16* __restrict__ OT,
                                                const float* __restrict__ rsums,
                                                float* __restrict__ out) {
  __shared__ float sc2[8][576];
  __shared__ float rb[1024];
  const int t = threadIdx.x;
  const int pb = blockIdx.x;
  const int p = pb >> 5, bh = pb & 31, b = bh >> 3, h = bh & 7;
  const int w = t >> 6, l = t & 63, g = l >> 4, li = l & 15;
  const int n0 = blockIdx.y * 128 + w * 16;
  const int abb = p * 32 + bh;
  const int obb = p ? bh : 32 + bh;
  const int aoff = p ? 0 : 32;
  const size_t rowbase = (size_t)(p * 4096 + b * 1024) * 768;
  rb[t] = rsums[(size_t)abb * 1024 + t];
  rb[t + 512] = rsums[(size_t)abb * 1024 + t + 512];
  __syncthreads();
  // K B-frag (col n=li): row n0+li
  half8 kf = *(const half8*)(qkvh + rowbase + (size_t)(n0 + li) * 768 + 256 + h * 32 + 8 * g);
  const f16* ob = OT + ((size_t)obb * 64 + aoff + li) * 1024 + 8 * g;
  f16 (*P)[40] = (f16(*)[40])&sc2[w][0];
  const f32x4 z = {0.f, 0.f, 0.f, 0.f};
  f32x4 u0 = z, u1 = z;
  for (int q0 = 0; q0 < 1024; q0 += 32) {
#pragma unroll
    for (int fq = 0; fq < 2; ++fq) {
      half8 qa = *(const half8*)(qkvh + rowbase + (size_t)(q0 + fq * 16 + li) * 768 + h * 32 + 8 * g);
      f32x4 s = __builtin_amdgcn_mfma_f32_16x16x32_f16(qa, kf, z, 0, 0, 0);
      union { f16 h[4]; uint2 u; } pk;
#pragma unroll
      for (int r = 0; r < 4; ++r)
        pk.h[r] = (f16)(__expf(s[r] * SCALE_F) * rb[q0 + fq * 16 + 4 * g + r]);
      *(uint2*)&P[li][fq * 16 + 4 * g] = pk.u;
    }
    half8 pb0 = *(const half8*)&P[li][8 * g];
    half8 A0 = *(const half8*)(ob + q0);
    half8 A1 = *(const half8*)(ob + 16384 + q0);
    u0 = __builtin_amdgcn_mfma_f32_16x16x32_f16(A0, pb0, u0, 0, 0, 0);
    u1 = __builtin_amdgcn_mfma_f32_16x16x32_f16(A1, pb0, u1, 0, 0, 0);
  }
  // combine: alpha*U + 0.4*(OT[bh] + OT[32+bh]) rows aoff+d
  float (*Uw)[36] = (float(*)[36])&sc2[w][0];
#pragma unroll
  for (int df = 0; df < 2; ++df)
#pragma unroll
    for (int r = 0; r < 4; ++r) {
      const int d_l = df * 16 + 4 * g + r;
      float uu = df ? u1[r] : u0[r];
      float a1 = (float)OT[((size_t)bh * 64 + aoff + d_l) * 1024 + n0 + li];
      float a2 = (float)OT[((size_t)(32 + bh) * 64 + aoff + d_l) * 1024 + n0 + li];
      Uw[li][d_l] = ALPHA_F * uu + OMA_F * (a1 + a2);
    }
  const int nn = l >> 2, dq = (l & 3) * 8;
  f32x4 v0 = *(const f32x4*)&Uw[nn][dq];
  f32x4 v1 = *(const f32x4*)&Uw[nn][dq + 4];
  float* dst = out + ((size_t)((1 - p) * 4 + b) * 1024 + n0 + nn) * 256 + h * 32 + dq;
  *(f32x4*)dst = v0;
  *(f32x4*)(dst + 4) = v1;
}

// ---------------------------------------------------------------------------
extern "C" void kernel_launch(void* const* d_in, const int* in_sizes, int n_in,
                              void* d_out, int out_size, void* d_ws, size_t ws_size,
                              hipStream_t stream) {
  const float* x  = (const float*)d_in[0];
  const float* wr = (const float*)d_in[1];
  const float* wd = (const float*)d_in[2];
  float* out = (float*)d_out;
  char* ws = (char*)d_ws;
  f16* xh    = (f16*)(ws + WS_XH);
  f16* wh    = (f16*)(ws + WS_WH);
  f16* qkvh  = (f16*)(ws + WS_QKVH);
  f16* VT    = (f16*)(ws + WS_VT);
  f16* OT    = (f16*)(ws + WS_OT);
  float* rsums = (float*)(ws + WS_RS);

  k_cast<<<1216, 256, 0, stream>>>(x, wr, wd, xh, wh);
  k_projm<<<dim3(64, 12), 512, 0, stream>>>(xh, wh, qkvh, VT);
  k_fused1<<<dim3(64, 8), 512, 0, stream>>>(qkvh, VT, OT, rsums, out);
  k_fused2<<<dim3(64, 8), 512, 0, stream>>>(qkvh, OT, rsums, out);
}

// Round 6
// 70.275 us; speedup vs baseline: 5.9171x; 2.7284x over previous
//
#include <hip/hip_runtime.h>
#include <cstdint>
#include <cstddef>

// ---------------------------------------------------------------------------
// B=4, N=1024, C=256, H=8, hd=32, ALPHA=0.6
// softmax rows sum to 1 => S_x = attn_x^T; associativity kills the N^3 work.
// r6: all MFMA kernels LDS-staged (double-buffered, coalesced staging loads,
// issue-early/write-late) -- r5 was latency-bound on per-fragment global
// row-gathers re-issued by every wave. Fragment math identical to r5.
// ---------------------------------------------------------------------------

typedef _Float16 f16;
typedef _Float16 half8 __attribute__((ext_vector_type(8)));
typedef float f32x4 __attribute__((ext_vector_type(4)));

#define ALPHA_F 0.6f
#define OMA_F   0.4f
#define SCALE_F 0.17677669529663687f  // 1/sqrt(32)

static const size_t WS_XH   = 0;            //  4,194,304
static const size_t WS_WH   = 4194304ull;   //    786,432
static const size_t WS_QKVH = 4980736ull;   // 12,582,912
static const size_t WS_VT   = 17563648ull;  //  4,194,304
static const size_t WS_OT   = 21757952ull;  //  8,388,608
static const size_t WS_RS   = 30146560ull;  //    262,144

// ---------------------------------------------------------------------------
// K0: cast x -> xh[2][4096][256], w_r/w_d -> wh[2][768][256].  8 f16/thread.
__global__ __launch_bounds__(256) void k_cast(const float* __restrict__ x,
                                              const float* __restrict__ wr,
                                              const float* __restrict__ wd,
                                              f16* __restrict__ xh,
                                              f16* __restrict__ wh) {
  const int gid = blockIdx.x * 256 + threadIdx.x;
  if (gid < 262144) {
    const int i0 = gid * 8;
    const int k = i0 & 255, row = (i0 >> 8) & 4095, br = i0 >> 20;
    const float* src = x + (size_t)row * 512 + br * 256 + k;
    float4 a = *(const float4*)src;
    float4 b = *(const float4*)(src + 4);
    union { f16 h[8]; uint4 u; } pk;
    pk.h[0] = (f16)a.x; pk.h[1] = (f16)a.y; pk.h[2] = (f16)a.z; pk.h[3] = (f16)a.w;
    pk.h[4] = (f16)b.x; pk.h[5] = (f16)b.y; pk.h[6] = (f16)b.z; pk.h[7] = (f16)b.w;
    *(uint4*)(xh + i0) = pk.u;
  } else {
    const int i0 = (gid - 262144) * 8;
    const int br = (i0 >= 196608) ? 1 : 0;
    const int j = i0 - br * 196608;
    const float* w = br ? wd : wr;
    float4 a = *(const float4*)(w + j);
    float4 b = *(const float4*)(w + j + 4);
    union { f16 h[8]; uint4 u; } pk;
    pk.h[0] = (f16)a.x; pk.h[1] = (f16)a.y; pk.h[2] = (f16)a.z; pk.h[3] = (f16)a.w;
    pk.h[4] = (f16)b.x; pk.h[5] = (f16)b.y; pk.h[6] = (f16)b.z; pk.h[7] = (f16)b.w;
    *(uint4*)(wh + i0) = pk.u;
  }
}

// ---------------------------------------------------------------------------
// K1: proj MFMA GEMM, LDS-staged.  Block 512=8 waves; m-tile 128, j-tile 64.
// Ws staged once (padded, conflict-free); Xs double-buffered k-chunks.
__global__ __launch_bounds__(512) void k_projm(const f16* __restrict__ xh,
                                               const f16* __restrict__ wh,
                                               f16* __restrict__ qkvh,
                                               f16* __restrict__ VT) {
  __shared__ f16 Ws[64][264];
  __shared__ f16 Xs[2][128][32];
  __shared__ f16 sc[8][64][24];
  const int t = threadIdx.x;
  const int w = t >> 6, l = t & 63, g = l >> 4, li = l & 15;
  const int m0 = blockIdx.x * 128;
  const int j0 = blockIdx.y * 64;
  const int br = m0 >> 12;
  const int mrow = m0 & 4095;
  const bool qk = (j0 < 512);
  // stage W (64 rows x 256 dims, pad 8)
#pragma unroll
  for (int ps = 0; ps < 4; ++ps) {
    const int idx = ps * 512 + t;
    const int wr_ = idx >> 5, wc8 = (idx & 31) * 8;
    uint4 wv = *(const uint4*)(wh + (size_t)(br * 768 + j0 + wr_) * 256 + wc8);
    *(uint4*)&Ws[wr_][wc8] = wv;
  }
  // stage X chunk 0
  const int xrow = t >> 2, xc8 = (t & 3) * 8;
  const f16* xgl = xh + (size_t)(br * 4096 + mrow + xrow) * 256 + xc8;
  uint4 xreg = *(const uint4*)xgl;
  *(uint4*)&Xs[0][xrow][xc8] = xreg;
  const f32x4 z = {0.f, 0.f, 0.f, 0.f};
  f32x4 c[4] = {z, z, z, z};
  int cur = 0;
  for (int kc = 0; kc < 8; ++kc, cur ^= 1) {
    __syncthreads();
    if (kc < 7) xreg = *(const uint4*)(xgl + (kc + 1) * 32);
    half8 xa = *(const half8*)&Xs[cur][w * 16 + li][8 * g];
    if (qk) {
#pragma unroll
      for (int jf = 0; jf < 4; ++jf) {
        half8 wa = *(const half8*)&Ws[jf * 16 + li][kc * 32 + 8 * g];
        c[jf] = __builtin_amdgcn_mfma_f32_16x16x32_f16(wa, xa, c[jf], 0, 0, 0);
      }
    } else {
#pragma unroll
      for (int jf = 0; jf < 4; ++jf) {
        half8 wa = *(const half8*)&Ws[jf * 16 + li][kc * 32 + 8 * g];
        c[jf] = __builtin_amdgcn_mfma_f32_16x16x32_f16(xa, wa, c[jf], 0, 0, 0);
      }
    }
    if (kc < 7) *(uint4*)&Xs[cur ^ 1][xrow][xc8] = xreg;
  }
  if (qk) {
    // C[j][n]: col n=li, rows j=j0+jf*16+4g+r  -> Qw[n][j] rows [16][72]
    f16 (*Qw)[72] = (f16(*)[72])&sc[w][0][0];
#pragma unroll
    for (int jf = 0; jf < 4; ++jf) {
      union { f16 h[4]; uint2 u; } pk;
#pragma unroll
      for (int r = 0; r < 4; ++r) pk.h[r] = (f16)c[jf][r];
      *(uint2*)&Qw[li][jf * 16 + 4 * g] = pk.u;
    }
    const int n = l >> 2, jc = (l & 3) * 16;
    uint4 v0 = *(const uint4*)&Qw[n][jc];
    uint4 v1 = *(const uint4*)&Qw[n][jc + 8];
    f16* dst = qkvh + (size_t)(m0 + w * 16 + n) * 768 + j0 + jc;
    *(uint4*)dst = v0;
    *(uint4*)(dst + 8) = v1;
  } else {
    // C[n][j]: col j=j0+jf*16+li, rows n=4g+r -> Vw[j][n] rows [64][24]
    f16 (*Vw)[24] = (f16(*)[24])&sc[w][0][0];
#pragma unroll
    for (int jf = 0; jf < 4; ++jf) {
      union { f16 h[4]; uint2 u; } pk;
#pragma unroll
      for (int r = 0; r < 4; ++r) pk.h[r] = (f16)c[jf][r];
      *(uint2*)&Vw[jf * 16 + li][4 * g] = pk.u;
    }
    const int jg = j0 + l - 512;
    const int hh = jg >> 5, dd = jg & 31;
    const int b = mrow >> 10;
    const int nn = (mrow & 1023) + w * 16;
    uint4 v0 = *(const uint4*)&Vw[l][0];
    uint4 v1 = *(const uint4*)&Vw[l][8];
    f16* dst = VT + ((size_t)(b * 8 + hh) * 64 + br * 32 + dd) * 1024 + nn;
    *(uint4*)dst = v0;
    *(uint4*)(dst + 8) = v1;
  }
}

// ---------------------------------------------------------------------------
// K2: fused flash pass, LDS-staged.  Block 512=8 waves, wave owns 16 q-rows.
// K/V tiles (128 keys) double-buffered; fragment math identical to r5.
__global__ __launch_bounds__(512) void k_fused1(const f16* __restrict__ qkvh,
                                                const f16* __restrict__ VT,
                                                f16* __restrict__ OT,
                                                float* __restrict__ rsums,
                                                float* __restrict__ out) {
  __shared__ f16 Ks[2][128][32];
  __shared__ f16 Vs[2][64][136];
  __shared__ f16 scw[8][1536];
  __shared__ float rsh[8][16];
  const int t = threadIdx.x;
  const int bb = blockIdx.x;
  const int br = bb >> 5, bh = bb & 31, b = bh >> 3, h = bh & 7;
  const int w = t >> 6, l = t & 63, g = l >> 4, li = l & 15;
  const int q0 = blockIdx.y * 128 + w * 16;
  const size_t rowbase = (size_t)(br * 4096 + b * 1024) * 768;
  half8 qf = *(const half8*)(qkvh + rowbase + (size_t)(q0 + li) * 768 + h * 32 + 8 * g);
  // staging roles: K 128x32 (4 thr/row), V 64x128 (8 thr/row, 2 chunks)
  const int krow = t >> 2, kc8 = (t & 3) * 8;
  const int vrow = t >> 3, vc8 = (t & 7) * 8;
  const f16* kgl = qkvh + rowbase + (size_t)krow * 768 + 256 + h * 32 + kc8;
  const f16* vgl = VT + ((size_t)bh * 64 + vrow) * 1024 + vc8;
  uint4 kreg = *(const uint4*)kgl;
  uint4 vreg0 = *(const uint4*)vgl;
  uint4 vreg1 = *(const uint4*)(vgl + 64);
  *(uint4*)&Ks[0][krow][kc8] = kreg;
  *(uint4*)&Vs[0][vrow][vc8] = vreg0;
  *(uint4*)&Vs[0][vrow][64 + vc8] = vreg1;
  f16 (*P)[72] = (f16(*)[72])&scw[w][0];
  const f32x4 z = {0.f, 0.f, 0.f, 0.f};
  f32x4 o[4] = {z, z, z, z};
  float qsum = 0.f;
  int cur = 0;
  for (int tile = 0; tile < 8; ++tile, cur ^= 1) {
    __syncthreads();
    if (tile < 7) {
      const int m1 = (tile + 1) * 128;
      kreg = *(const uint4*)(kgl + (size_t)m1 * 768);
      vreg0 = *(const uint4*)(vgl + m1);
      vreg1 = *(const uint4*)(vgl + m1 + 64);
    }
#pragma unroll
    for (int kh = 0; kh < 2; ++kh) {
      f32x4 sct[4];
#pragma unroll
      for (int ct = 0; ct < 4; ++ct) {
        half8 ka = *(const half8*)&Ks[cur][kh * 64 + ct * 16 + li][8 * g];
        sct[ct] = __builtin_amdgcn_mfma_f32_16x16x32_f16(ka, qf, z, 0, 0, 0);
      }
#pragma unroll
      for (int ct = 0; ct < 4; ++ct) {
        union { f16 hh[4]; uint2 u; } pk;
#pragma unroll
        for (int r = 0; r < 4; ++r) {
          float p = __expf(sct[ct][r] * SCALE_F);
          qsum += p;
          pk.hh[r] = (f16)p;
        }
        *(uint2*)&P[li][ct * 16 + 4 * g] = pk.u;
      }
#pragma unroll
      for (int kk = 0; kk < 2; ++kk) {
        half8 pa = *(const half8*)&P[li][kk * 32 + 8 * g];
#pragma unroll
        for (int jf = 0; jf < 4; ++jf) {
          half8 vv = *(const half8*)&Vs[cur][jf * 16 + li][kh * 64 + kk * 32 + 8 * g];
          o[jf] = __builtin_amdgcn_mfma_f32_16x16x32_f16(pa, vv, o[jf], 0, 0, 0);
        }
      }
    }
    if (tile < 7) {
      *(uint4*)&Ks[cur ^ 1][krow][kc8] = kreg;
      *(uint4*)&Vs[cur ^ 1][vrow][vc8] = vreg0;
      *(uint4*)&Vs[cur ^ 1][vrow][64 + vc8] = vreg1;
    }
  }
  qsum += __shfl_xor(qsum, 16, 64);
  qsum += __shfl_xor(qsum, 32, 64);
  const float rinv = 1.0f / qsum;
  if (l < 16) {
    rsh[w][li] = rinv;
    rsums[(size_t)bb * 1024 + q0 + li] = rinv;
  }
  float rv[4];
#pragma unroll
  for (int r = 0; r < 4; ++r) rv[r] = rsh[w][4 * g + r];
#pragma unroll
  for (int jf = 0; jf < 4; ++jf)
#pragma unroll
    for (int r = 0; r < 4; ++r) o[jf][r] *= rv[r];
  // ---- out_r / out_d straight from registers ----
  {
    const int jf0 = br * 2;
    float* obase = out + ((size_t)((2 + br) * 4 + b) * 1024 + q0 + 4 * g) * 256 + h * 32 + li;
#pragma unroll
    for (int jf2 = 0; jf2 < 2; ++jf2)
#pragma unroll
      for (int r = 0; r < 4; ++r)
        obase[(size_t)r * 256 + jf2 * 16] = o[jf0 + jf2][r];
  }
  // ---- transpose O (16q x 64j) -> Ow[j][q] rows [64][24], then OT ----
  f16 (*Ow)[24] = (f16(*)[24])&scw[w][0];
#pragma unroll
  for (int jf = 0; jf < 4; ++jf)
#pragma unroll
    for (int rp = 0; rp < 2; ++rp) {
      union { f16 h[2]; unsigned int u; } pk2;
      pk2.h[0] = (f16)o[jf][2 * rp];
      pk2.h[1] = (f16)o[jf][2 * rp + 1];
      *(unsigned int*)&Ow[jf * 16 + li][4 * g + 2 * rp] = pk2.u;
    }
  {
    uint4 v0 = *(const uint4*)&Ow[l][0];
    uint4 v1 = *(const uint4*)&Ow[l][8];
    f16* dst = OT + ((size_t)bb * 64 + l) * 1024 + q0;
    *(uint4*)dst = v0;
    *(uint4*)(dst + 8) = v1;
  }
}

// ---------------------------------------------------------------------------
// K3: fused recompute + U + combine, LDS-staged.  Block 512=8 waves, wave
// owns 16 n-cols.  Q/OT tiles (128 q) double-buffered.
__global__ __launch_bounds__(512) void k_fused2(const f16* __restrict__ qkvh,
                                                const f16* __restrict__ OT,
                                                const float* __restrict__ rsums,
                                                float* __restrict__ out) {
  __shared__ f16 Qs[2][128][32];
  __shared__ f16 Os[2][32][136];
  __shared__ float sc2[8][1088];
  __shared__ float rb[1024];
  const int t = threadIdx.x;
  const int pb = blockIdx.x;
  const int p = pb >> 5, bh = pb & 31, b = bh >> 3, h = bh & 7;
  const int w = t >> 6, l = t & 63, g = l >> 4, li = l & 15;
  const int n0 = blockIdx.y * 128 + w * 16;
  const int abb = p * 32 + bh;
  const int obb = p ? bh : 32 + bh;
  const int aoff = p ? 0 : 32;
  const size_t rowbase = (size_t)(p * 4096 + b * 1024) * 768;
  rb[t] = rsums[(size_t)abb * 1024 + t];
  rb[t + 512] = rsums[(size_t)abb * 1024 + t + 512];
  half8 kf = *(const half8*)(qkvh + rowbase + (size_t)(n0 + li) * 768 + 256 + h * 32 + 8 * g);
  // staging roles: Q 128x32 (4 thr/row), O 32x128 (16 thr/row)
  const int qrow = t >> 2, qc8 = (t & 3) * 8;
  const int orow = t >> 4, oc8 = (t & 15) * 8;
  const f16* qgl = qkvh + rowbase + (size_t)qrow * 768 + h * 32 + qc8;
  const f16* ogl = OT + ((size_t)obb * 64 + aoff + orow) * 1024 + oc8;
  uint4 qreg = *(const uint4*)qgl;
  uint4 oreg = *(const uint4*)ogl;
  *(uint4*)&Qs[0][qrow][qc8] = qreg;
  *(uint4*)&Os[0][orow][oc8] = oreg;
  f16 (*P)[136] = (f16(*)[136])&sc2[w][0];
  const f32x4 z = {0.f, 0.f, 0.f, 0.f};
  f32x4 u0 = z, u1 = z;
  int cur = 0;
  for (int tile = 0; tile < 8; ++tile, cur ^= 1) {
    __syncthreads();
    if (tile < 7) {
      const int q1 = (tile + 1) * 128;
      qreg = *(const uint4*)(qgl + (size_t)q1 * 768);
      oreg = *(const uint4*)(ogl + q1);
    }
    const int qt0 = tile * 128;
#pragma unroll
    for (int fq = 0; fq < 8; ++fq) {
      half8 qa = *(const half8*)&Qs[cur][fq * 16 + li][8 * g];
      f32x4 s = __builtin_amdgcn_mfma_f32_16x16x32_f16(qa, kf, z, 0, 0, 0);
      union { f16 hh[4]; uint2 u; } pk;
#pragma unroll
      for (int r = 0; r < 4; ++r)
        pk.hh[r] = (f16)(__expf(s[r] * SCALE_F) * rb[qt0 + fq * 16 + 4 * g + r]);
      *(uint2*)&P[li][fq * 16 + 4 * g] = pk.u;
    }
#pragma unroll
    for (int kk = 0; kk < 4; ++kk) {
      half8 pbf = *(const half8*)&P[li][kk * 32 + 8 * g];
      half8 A0 = *(const half8*)&Os[cur][li][kk * 32 + 8 * g];
      half8 A1 = *(const half8*)&Os[cur][16 + li][kk * 32 + 8 * g];
      u0 = __builtin_amdgcn_mfma_f32_16x16x32_f16(A0, pbf, u0, 0, 0, 0);
      u1 = __builtin_amdgcn_mfma_f32_16x16x32_f16(A1, pbf, u1, 0, 0, 0);
    }
    if (tile < 7) {
      *(uint4*)&Qs[cur ^ 1][qrow][qc8] = qreg;
      *(uint4*)&Os[cur ^ 1][orow][oc8] = oreg;
    }
  }
  // combine: alpha*U + 0.4*(OT[bh] + OT[32+bh]) rows aoff+d
  float (*Uw)[36] = (float(*)[36])&sc2[w][0];
#pragma unroll
  for (int df = 0; df < 2; ++df)
#pragma unroll
    for (int r = 0; r < 4; ++r) {
      const int d_l = df * 16 + 4 * g + r;
      float uu = df ? u1[r] : u0[r];
      float a1 = (float)OT[((size_t)bh * 64 + aoff + d_l) * 1024 + n0 + li];
      float a2 = (float)OT[((size_t)(32 + bh) * 64 + aoff + d_l) * 1024 + n0 + li];
      Uw[li][d_l] = ALPHA_F * uu + OMA_F * (a1 + a2);
    }
  const int nn = l >> 2, dq = (l & 3) * 8;
  f32x4 v0 = *(const f32x4*)&Uw[nn][dq];
  f32x4 v1 = *(const f32x4*)&Uw[nn][dq + 4];
  float* dst = out + ((size_t)((1 - p) * 4 + b) * 1024 + n0 + nn) * 256 + h * 32 + dq;
  *(f32x4*)dst = v0;
  *(f32x4*)(dst + 4) = v1;
}

// ---------------------------------------------------------------------------
extern "C" void kernel_launch(void* const* d_in, const int* in_sizes, int n_in,
                              void* d_out, int out_size, void* d_ws, size_t ws_size,
                              hipStream_t stream) {
  const float* x  = (const float*)d_in[0];
  const float* wr = (const float*)d_in[1];
  const float* wd = (const float*)d_in[2];
  float* out = (float*)d_out;
  char* ws = (char*)d_ws;
  f16* xh    = (f16*)(ws + WS_XH);
  f16* wh    = (f16*)(ws + WS_WH);
  f16* qkvh  = (f16*)(ws + WS_QKVH);
  f16* VT    = (f16*)(ws + WS_VT);
  f16* OT    = (f16*)(ws + WS_OT);
  float* rsums = (float*)(ws + WS_RS);

  k_cast<<<1216, 256, 0, stream>>>(x, wr, wd, xh, wh);
  k_projm<<<dim3(64, 12), 512, 0, stream>>>(xh, wh, qkvh, VT);
  k_fused1<<<dim3(64, 8), 512, 0, stream>>>(qkvh, VT, OT, rsums, out);
  k_fused2<<<dim3(64, 8), 512, 0, stream>>>(qkvh, OT, rsums, out);
}